// Round 6
// baseline (327.746 us; speedup 1.0000x reference)
//
#include <hip/hip_runtime.h>
#include <hip/hip_bf16.h>

// Problem: B=1024, S=64, E=256, H=512, V=128, C=32
#define BB 1024
#define SS 64
#define EE 256
#define HH 512
#define VV 128
#define CC 32

typedef _Float16 f16;
typedef _Float16 f16x4 __attribute__((ext_vector_type(4)));
typedef _Float16 f16x8 __attribute__((ext_vector_type(8)));
typedef float    f32x4 __attribute__((ext_vector_type(4)));

// ---------------------------------------------------------------------------
// P[v][h] = emb[v,:] . W_ih[h,:] + b_ih[h] + b_hh[h]  (f16 output table)
// ---------------------------------------------------------------------------
__global__ __launch_bounds__(256) void prep_P(
    const float* __restrict__ emb, const float* __restrict__ W_ih,
    const float* __restrict__ b_ih, const float* __restrict__ b_hh,
    f16* __restrict__ P)
{
    __shared__ float er[EE];
    const int v = blockIdx.x;
    for (int i = threadIdx.x; i < EE; i += 256) er[i] = emb[(size_t)v * EE + i];
    __syncthreads();
    for (int h = threadIdx.x; h < HH; h += 256) {
        const float4* wr = (const float4*)(W_ih + (size_t)h * EE);
        float s = 0.f;
        #pragma unroll 4
        for (int e4 = 0; e4 < EE / 4; ++e4) {
            float4 w = wr[e4];
            const float* e = er + e4 * 4;
            s += w.x * e[0] + w.y * e[1] + w.z * e[2] + w.w * e[3];
        }
        P[(size_t)v * HH + h] = (f16)(s + b_ih[h] + b_hh[h]);
    }
}

// ---------------------------------------------------------------------------
// RNN, zero inter-block communication. 64 blocks x 512 threads (8 waves).
// Block owns 16 batch rows and computes ALL 512 h-cols. W_hh (512x512 f16):
// k 0..383 in registers (bfr[4][12] = 192 VGPR/lane), k 384..511 in static
// LDS (128 KB).
//
// REGISTER BUDGET, round-6 attempt: every __launch_bounds__-based spelling
// ((512,2), (512,1), +amdgpu_waves_per_eu stacked on launch_bounds, 1024thr)
// left the allocator at a 128-VGPR budget (= 512-reg pool / 4-waves-per-EU
// default target) and it spilled ~120 regs/lane of bfr to scratch
// (24 MB/dispatch scratch writes, L2-latency reloads every step, MfmaUtil
// 6%). Hypothesis: HIP's __launch_bounds__ macro's own waves-per-eu
// derivation clobbers the explicit attribute. So: NO __launch_bounds__ at
// all — raw clang attributes only:
//   amdgpu_flat_work_group_size(512,512)  (what launch_bounds(512) gives)
//   amdgpu_waves_per_eu(2,2)              (pin scheduler model: 2 waves/EU)
//   amdgpu_num_vgpr(256)                  (direct register-budget request)
// LDS (148.5 KB) already limits the CU to ONE block = 2 waves/EU, so 256
// regs costs zero occupancy. If this is STILL 128/24MB, the allocator path
// is exhausted -> next round pivots to a design-to-128 L2-streaming W.
//
// MFMA operands SWAPPED: D = W_tile * h^T.
//   lane(lrow,quad), reg r -> h_next[batch=lrow][col = n0w + 16t + 4*quad + r]
// Each lane owns 4 consecutive h-cols of ONE batch row:
//   - hbuf epilogue write: 4x ds_write_b64
//   - P addend: 4x 8-byte global loads (P is 128 KB, L2-resident), issued
//     AFTER the MFMA phase (short live range -> lower peak pressure during
//     the 192-reg bfr region); latency hides under barrier convergence.
// ---------------------------------------------------------------------------
#define KSREG 12           // k-steps (of 32) held in registers
#define KSLDS 4            // k-steps held in LDS
#define HSTR  520          // hbuf stride in f16 (1040 B: 8B-aligned, +4-bank skew)

__global__
__attribute__((amdgpu_flat_work_group_size(512, 512)))
__attribute__((amdgpu_waves_per_eu(2, 2)))
__attribute__((amdgpu_num_vgpr(256)))
void rnn_kernel(
    const int* __restrict__ x_in, const int* __restrict__ x_lens,
    const float* __restrict__ W_hh, const f16* __restrict__ P,
    f16* __restrict__ last)
{
    __shared__ __align__(16) f16 hbuf[16 * HSTR];                // 16.3 KB
    __shared__ __align__(16) f16 wlds[8 * 4 * KSLDS * 64 * 8];   // 128 KB
    __shared__ int xin[16 * SS];                                 // 4 KB
    __shared__ int lens[16];

    const int tid  = threadIdx.x;
    const int r0   = blockIdx.x * 16;
    const int wave = tid >> 6;       // 0..7 -> cols [64w, 64w+64)
    const int lane = tid & 63;
    const int lrow = lane & 15;      // batch row (as B-operand n / C col)
    const int quad = lane >> 4;
    const int n0w  = wave * 64;

    // ---- one-time: W_hh -> register fragments + LDS fragments (f32->f16) ----
    // frag[k][n] = W_hh[n][k]; lane holds n = lrow (+16t+64w), k = 32ks+8quad+j
    f16x8 bfr[4][KSREG];
    #pragma unroll
    for (int t = 0; t < 4; ++t) {
        const float* wr = W_hh + (size_t)(n0w + 16 * t + lrow) * HH + quad * 8;
        #pragma unroll
        for (int ks = 0; ks < KSREG; ++ks) {
            float4 x0 = *(const float4*)(wr + ks * 32);
            float4 x1 = *(const float4*)(wr + ks * 32 + 4);
            f16x8 b;
            b[0] = (f16)x0.x; b[1] = (f16)x0.y; b[2] = (f16)x0.z; b[3] = (f16)x0.w;
            b[4] = (f16)x1.x; b[5] = (f16)x1.y; b[6] = (f16)x1.z; b[7] = (f16)x1.w;
            bfr[t][ks] = b;
        }
        #pragma unroll
        for (int ks = 0; ks < KSLDS; ++ks) {
            float4 x0 = *(const float4*)(wr + (KSREG + ks) * 32);
            float4 x1 = *(const float4*)(wr + (KSREG + ks) * 32 + 4);
            f16x8 b;
            b[0] = (f16)x0.x; b[1] = (f16)x0.y; b[2] = (f16)x0.z; b[3] = (f16)x0.w;
            b[4] = (f16)x1.x; b[5] = (f16)x1.y; b[6] = (f16)x1.z; b[7] = (f16)x1.w;
            // swizzled: lane-consecutive 16B chunks, conflict-free b128 reads
            *(f16x8*)(wlds + ((((wave * 4 + t) * KSLDS + ks) * 64 + lane) << 3)) = b;
        }
    }

    // ---- LDS init: token tile, lengths (hbuf needs no init: st=0 writes all)
    for (int i = tid; i < 16 * (SS / 4); i += 512)
        ((int4*)xin)[i] = ((const int4*)(x_in + (size_t)r0 * SS))[i];
    if (tid < 16) lens[tid] = x_lens[r0 + tid];
    __syncthreads();

    const int   mylen = lens[lrow];
    const f16*  arow  = hbuf + lrow * HSTR + quad * 8;           // B-operand reads
    f16*        hwr   = hbuf + lrow * HSTR + n0w + quad * 4;     // epilogue writes
    f16*        lwr   = last + (size_t)(r0 + lrow) * HH + n0w + quad * 4;
    const f16*  pbase = P + n0w + quad * 4;

    for (int st = 0; st < SS; ++st) {
        // ---- MFMA: D = W_tile * h^T, 64 cols/wave x 16 rows, K = 512 ----
        f32x4 acc0 = {0,0,0,0}, acc1 = {0,0,0,0}, acc2 = {0,0,0,0}, acc3 = {0,0,0,0};
        if (st) {   // h_0 = 0 -> skip the whole matmul at step 0
            #pragma unroll
            for (int ks = 0; ks < KSREG; ++ks) {
                f16x8 a = *(const f16x8*)(arow + ks * 32);
                acc0 = __builtin_amdgcn_mfma_f32_16x16x32_f16(bfr[0][ks], a, acc0, 0, 0, 0);
                acc1 = __builtin_amdgcn_mfma_f32_16x16x32_f16(bfr[1][ks], a, acc1, 0, 0, 0);
                acc2 = __builtin_amdgcn_mfma_f32_16x16x32_f16(bfr[2][ks], a, acc2, 0, 0, 0);
                acc3 = __builtin_amdgcn_mfma_f32_16x16x32_f16(bfr[3][ks], a, acc3, 0, 0, 0);
            }
            #pragma unroll
            for (int ks = 0; ks < KSLDS; ++ks) {
                f16x8 a  = *(const f16x8*)(arow + (KSREG + ks) * 32);
                f16x8 b0 = *(const f16x8*)(wlds + ((((wave * 4 + 0) * KSLDS + ks) * 64 + lane) << 3));
                f16x8 b1 = *(const f16x8*)(wlds + ((((wave * 4 + 1) * KSLDS + ks) * 64 + lane) << 3));
                f16x8 b2 = *(const f16x8*)(wlds + ((((wave * 4 + 2) * KSLDS + ks) * 64 + lane) << 3));
                f16x8 b3 = *(const f16x8*)(wlds + ((((wave * 4 + 3) * KSLDS + ks) * 64 + lane) << 3));
                acc0 = __builtin_amdgcn_mfma_f32_16x16x32_f16(b0, a, acc0, 0, 0, 0);
                acc1 = __builtin_amdgcn_mfma_f32_16x16x32_f16(b1, a, acc1, 0, 0, 0);
                acc2 = __builtin_amdgcn_mfma_f32_16x16x32_f16(b2, a, acc2, 0, 0, 0);
                acc3 = __builtin_amdgcn_mfma_f32_16x16x32_f16(b3, a, acc3, 0, 0, 0);
            }
        }

        // P addend for THIS step: issued post-MFMA, consumed right after the
        // barrier -> latency hides under barrier convergence; short live range.
        const int  tok = xin[lrow * SS + st];
        const f16* pb  = pbase + (size_t)tok * HH;
        f16x4 pv0 = *(const f16x4*)(pb);
        f16x4 pv1 = *(const f16x4*)(pb + 16);
        f16x4 pv2 = *(const f16x4*)(pb + 32);
        f16x4 pv3 = *(const f16x4*)(pb + 48);

        __syncthreads();  // all waves done reading hbuf for this step

        // ---- epilogue: h_{st+1}[lrow][n0w+16t+4q+r] = tanh(acc{t}[r] + P)
        const int tp1 = st + 1;
        const bool wr_last = (mylen == tp1);
        #pragma unroll
        for (int t = 0; t < 4; ++t) {
            const f32x4 acc = (t == 0) ? acc0 : (t == 1) ? acc1 : (t == 2) ? acc2 : acc3;
            const f16x4 pv  = (t == 0) ? pv0  : (t == 1) ? pv1  : (t == 2) ? pv2  : pv3;
            f16x4 hv;
            #pragma unroll
            for (int r = 0; r < 4; ++r) {
                float z = acc[r] + (float)pv[r];
                // tanh(z) = 1 - 2/(e^{2z}+1); exp over/underflow saturate correctly
                float e = __expf(2.f * z);
                hv[r] = (f16)(1.f - 2.f / (e + 1.f));
            }
            *(f16x4*)(hwr + 16 * t) = hv;
            if (wr_last) *(f16x4*)(lwr + 16 * t) = hv;
        }

        __syncthreads();  // epilogue done: next step may read new hbuf
    }
}

// ---------------------------------------------------------------------------
// MLP layer 1 via MFMA: hidden = relu(last @ W1^T + b1). 512 blocks,
// block = (group g of 16 rows) x (slice of 64 cols); wave owns ONE 16-col
// tile -> bfr[16] = 64 VGPR, fits the 128-reg default budget.
// ---------------------------------------------------------------------------
__global__ __launch_bounds__(256, 1)
void mlp1_kernel(
    const f16* __restrict__ last, const float* __restrict__ W1,
    const float* __restrict__ b1, f16* __restrict__ hidden)
{
    __shared__ __align__(16) f16 hb[16 * HSTR];
    const int tid   = threadIdx.x;
    const int g     = blockIdx.x & 63;
    const int slice = blockIdx.x >> 6;       // 0..7
    const int r0    = g * 16;
    const int n0    = slice * 64;
    const int wave  = tid >> 6;              // 0..3
    const int lane  = tid & 63;
    const int lrow  = lane & 15;
    const int quad  = lane >> 4;

    f16x8 bfr[16];
    {
        const float* wr = W1 + (size_t)(n0 + wave * 16 + lrow) * HH + quad * 8;
        #pragma unroll
        for (int K0 = 0; K0 < 16; ++K0) {
            float4 x0 = *(const float4*)(wr + K0 * 32);
            float4 x1 = *(const float4*)(wr + K0 * 32 + 4);
            f16x8 b;
            b[0] = (f16)x0.x; b[1] = (f16)x0.y; b[2] = (f16)x0.z; b[3] = (f16)x0.w;
            b[4] = (f16)x1.x; b[5] = (f16)x1.y; b[6] = (f16)x1.z; b[7] = (f16)x1.w;
            bfr[K0] = b;
        }
    }

    for (int i = tid; i < 16 * (HH / 8); i += 256) {
        const int row = i >> 6;
        const int c8  = (i & 63) * 8;
        *(float4*)(hb + row * HSTR + c8) =
            *(const float4*)(last + (size_t)(r0 + row) * HH + c8);
    }
    __syncthreads();

    f32x4 acc = {0,0,0,0};
    const f16* arow = hb + lrow * HSTR + quad * 8;
    #pragma unroll
    for (int K0 = 0; K0 < 16; ++K0) {
        f16x8 a = *(const f16x8*)(arow + K0 * 32);
        acc = __builtin_amdgcn_mfma_f32_16x16x32_f16(a, bfr[K0], acc, 0, 0, 0);
    }
    {
        const int cloc = wave * 16 + lrow;
        const float bb = b1[n0 + cloc];
        #pragma unroll
        for (int r = 0; r < 4; ++r) {
            const int row = quad * 4 + r;
            hidden[(size_t)(r0 + row) * HH + n0 + cloc] =
                (f16)fmaxf(acc[r] + bb, 0.f);
        }
    }
}

// ---------------------------------------------------------------------------
// logits = hidden @ W2^T + b2  (1024x32, K=512) — small, fp32 VALU
// ---------------------------------------------------------------------------
__global__ __launch_bounds__(256) void mlp2_kernel(
    const f16* __restrict__ hidden, const float* __restrict__ W2,
    const float* __restrict__ b2, float* __restrict__ out)
{
    __shared__ float hs[8][512];
    const int b0 = blockIdx.x * 8;
    for (int i = threadIdx.x; i < 8 * 512; i += 256)
        hs[i >> 9][i & 511] = (float)hidden[(size_t)(b0 + (i >> 9)) * HH + (i & 511)];
    __syncthreads();
    const int r = threadIdx.x >> 5, c = threadIdx.x & 31;
    const float4* w = (const float4*)(W2 + (size_t)c * HH);
    float acc = 0.f;
    #pragma unroll 4
    for (int k4 = 0; k4 < 128; ++k4) {
        float4 wv = w[k4];
        float4 hv = *(const float4*)(&hs[r][k4 * 4]);
        acc += wv.x * hv.x + wv.y * hv.y + wv.z * hv.z + wv.w * hv.w;
    }
    out[(size_t)(b0 + r) * CC + c] = acc + b2[c];
}

// ---------------------------------------------------------------------------
extern "C" void kernel_launch(void* const* d_in, const int* in_sizes, int n_in,
                              void* d_out, int out_size, void* d_ws, size_t ws_size,
                              hipStream_t stream)
{
    const int*   x_in   = (const int*)d_in[0];
    const int*   x_lens = (const int*)d_in[1];
    const float* emb    = (const float*)d_in[2];
    const float* W_ih   = (const float*)d_in[3];
    const float* b_ih   = (const float*)d_in[4];
    const float* W_hh   = (const float*)d_in[5];
    const float* b_hh   = (const float*)d_in[6];
    const float* W1     = (const float*)d_in[7];
    const float* b1     = (const float*)d_in[8];
    const float* W2     = (const float*)d_in[9];
    const float* b2     = (const float*)d_in[10];
    float* out = (float*)d_out;

    // workspace carve (re-poisoned every launch; everything rewritten below)
    char* ws = (char*)d_ws;
    f16* P      = (f16*)ws;                             // 128 KiB (slot 256 KiB)
    f16* last   = (f16*)(ws + (256 << 10));             // 1 MiB
    f16* hidden = (f16*)(ws + (256 << 10) + (1 << 20)); // 1 MiB

    hipLaunchKernelGGL(prep_P, dim3(VV), dim3(256), 0, stream,
                       emb, W_ih, b_ih, b_hh, P);
    hipLaunchKernelGGL(rnn_kernel, dim3(BB / 16), dim3(512), 0, stream,
                       x_in, x_lens, W_hh, P, last);
    hipLaunchKernelGGL(mlp1_kernel, dim3(512), dim3(256), 0, stream,
                       last, W1, b1, hidden);
    hipLaunchKernelGGL(mlp2_kernel, dim3(BB / 8), dim3(256), 0, stream,
                       hidden, W2, b2, out);
}

// Round 7
// 299.480 us; speedup vs baseline: 1.0944x; 1.0944x over previous
//
#include <hip/hip_runtime.h>
#include <hip/hip_bf16.h>

// Problem: B=1024, S=64, E=256, H=512, V=128, C=32
#define BB 1024
#define SS 64
#define EE 256
#define HH 512
#define VV 128
#define CC 32

typedef _Float16 f16;
typedef _Float16 f16x4 __attribute__((ext_vector_type(4)));
typedef _Float16 f16x8 __attribute__((ext_vector_type(8)));
typedef float    f32x4 __attribute__((ext_vector_type(4)));

// ---------------------------------------------------------------------------
// P[v][h] = emb[v,:] . W_ih[h,:] + b_ih[h] + b_hh[h]  (f16 output table)
// ---------------------------------------------------------------------------
__global__ __launch_bounds__(256) void prep_P(
    const float* __restrict__ emb, const float* __restrict__ W_ih,
    const float* __restrict__ b_ih, const float* __restrict__ b_hh,
    f16* __restrict__ P)
{
    __shared__ float er[EE];
    const int v = blockIdx.x;
    for (int i = threadIdx.x; i < EE; i += 256) er[i] = emb[(size_t)v * EE + i];
    __syncthreads();
    for (int h = threadIdx.x; h < HH; h += 256) {
        const float4* wr = (const float4*)(W_ih + (size_t)h * EE);
        float s = 0.f;
        #pragma unroll 4
        for (int e4 = 0; e4 < EE / 4; ++e4) {
            float4 w = wr[e4];
            const float* e = er + e4 * 4;
            s += w.x * e[0] + w.y * e[1] + w.z * e[2] + w.w * e[3];
        }
        P[(size_t)v * HH + h] = (f16)(s + b_ih[h] + b_hh[h]);
    }
}

// ---------------------------------------------------------------------------
// Wf[n][k] = (f16) W_hh[n][k]  — one-time f32->f16 conversion so the rnn
// init is pure 16-B f16 loads (half the loads, no cvt chains, low pressure).
// ---------------------------------------------------------------------------
__global__ __launch_bounds__(256) void prep_W(
    const float* __restrict__ W_hh, f16* __restrict__ Wf)
{
    const int i = blockIdx.x * 256 + threadIdx.x;   // 65536 threads x 4 elems
    float4 x = ((const float4*)W_hh)[i];
    f16x4 y;
    y[0] = (f16)x.x; y[1] = (f16)x.y; y[2] = (f16)x.z; y[3] = (f16)x.w;
    *(f16x4*)(Wf + (size_t)i * 4) = y;
}

// ---------------------------------------------------------------------------
// RNN, zero inter-block communication. 64 blocks x 512 threads (8 waves).
// Block owns 16 batch rows and computes ALL 512 h-cols. W_hh (512x512 f16):
// k 0..383 in registers (bfr[4][12] = 192 VGPR/lane), k 384..511 in static
// LDS (128 KB).
//
// REGISTER STRATEGY (round-7): every attribute-based budget request
// ((512,2),(512,1), amdgpu_waves_per_eu, amdgpu_num_vgpr, 1024thr) left the
// allocator at a 128-VGPR target; its cost model spills the 48 loop-invariant
// bfr fragments to scratch because each MFMA needs only ONE fragment in regs
// at a time (spill/reload between uses is legal). The counter: ONE inline-asm
// statement per loop iteration that takes ALL 48 f16x8 fragments as "v"
// inputs -> 192 VGPRs simultaneously live at a single instruction -> a
// 128-reg allocation is impossible -> target abandoned -> no spilling.
// Demand ~250 <= 256 (the 2-waves/EU HW limit LDS already forces), so
// occupancy is unchanged and scratch traffic (24 MB/dispatch) disappears.
//
// MFMA operands SWAPPED: D = W_tile * h^T.
//   lane(lrow,quad), reg r -> h_next[batch=lrow][col = n0w + 16t + 4*quad + r]
// Each lane owns 4 consecutive h-cols of ONE batch row:
//   - hbuf epilogue write: 4x ds_write_b64
//   - P addend: 4x 8-byte global loads (P is 128 KB, L2-resident), issued
//     post-MFMA (short live range, hides under barrier convergence).
// ---------------------------------------------------------------------------
#define KSREG 12           // k-steps (of 32) held in registers
#define KSLDS 4            // k-steps held in LDS
#define HSTR  520          // hbuf stride in f16 (1040 B: 8B-aligned, +4-bank skew)

// the 48-operand residency-forcing asm (see comment above)
#define KB(t,k) "v"(bfr[t][k])
#define KBT(t)  KB(t,0), KB(t,1), KB(t,2), KB(t,3), KB(t,4), KB(t,5), \
                KB(t,6), KB(t,7), KB(t,8), KB(t,9), KB(t,10), KB(t,11)

__global__
__attribute__((amdgpu_flat_work_group_size(512, 512)))
__attribute__((amdgpu_waves_per_eu(2, 2)))
void rnn_kernel(
    const int* __restrict__ x_in, const int* __restrict__ x_lens,
    const f16* __restrict__ Wf, const f16* __restrict__ P,
    f16* __restrict__ last)
{
    __shared__ __align__(16) f16 hbuf[16 * HSTR];                // 16.3 KB
    __shared__ __align__(16) f16 wlds[8 * 4 * KSLDS * 64 * 8];   // 128 KB
    __shared__ int xin[16 * SS];                                 // 4 KB
    __shared__ int lens[16];

    const int tid  = threadIdx.x;
    const int r0   = blockIdx.x * 16;
    const int wave = tid >> 6;       // 0..7 -> cols [64w, 64w+64)
    const int lane = tid & 63;
    const int lrow = lane & 15;      // batch row (as B-operand n / C col)
    const int quad = lane >> 4;
    const int n0w  = wave * 64;

    // ---- one-time: Wf -> register fragments + LDS fragments ----
    // frag[k][n] = W_hh[n][k]; lane holds n = lrow (+16t+64w), k = 32ks+8quad+j
    f16x8 bfr[4][KSREG];
    #pragma unroll
    for (int t = 0; t < 4; ++t) {
        const f16* wr = Wf + (size_t)(n0w + 16 * t + lrow) * HH + quad * 8;
        #pragma unroll
        for (int ks = 0; ks < KSREG; ++ks)
            bfr[t][ks] = *(const f16x8*)(wr + ks * 32);
        #pragma unroll
        for (int ks = 0; ks < KSLDS; ++ks)
            // swizzled: lane-consecutive 16B chunks, conflict-free b128 reads
            *(f16x8*)(wlds + ((((wave * 4 + t) * KSLDS + ks) * 64 + lane) << 3)) =
                *(const f16x8*)(wr + (KSREG + ks) * 32);
    }

    // ---- LDS init: token tile, lengths (hbuf needs no init: st=0 writes all)
    for (int i = tid; i < 16 * (SS / 4); i += 512)
        ((int4*)xin)[i] = ((const int4*)(x_in + (size_t)r0 * SS))[i];
    if (tid < 16) lens[tid] = x_lens[r0 + tid];
    __syncthreads();

    const int   mylen = lens[lrow];
    const f16*  arow  = hbuf + lrow * HSTR + quad * 8;           // B-operand reads
    f16*        hwr   = hbuf + lrow * HSTR + n0w + quad * 4;     // epilogue writes
    f16*        lwr   = last + (size_t)(r0 + lrow) * HH + n0w + quad * 4;
    const f16*  pbase = P + n0w + quad * 4;

    for (int st = 0; st < SS; ++st) {
        // Force all 48 W fragments simultaneously resident at ONE instruction
        // each iteration: defeats the allocator's spill-to-128 plan (see top).
        asm volatile("" :: KBT(0), KBT(1), KBT(2), KBT(3));

        // ---- MFMA: D = W_tile * h^T, 64 cols/wave x 16 rows, K = 512 ----
        f32x4 acc0 = {0,0,0,0}, acc1 = {0,0,0,0}, acc2 = {0,0,0,0}, acc3 = {0,0,0,0};
        if (st) {   // h_0 = 0 -> skip the whole matmul at step 0
            #pragma unroll
            for (int ks = 0; ks < KSREG; ++ks) {
                f16x8 a = *(const f16x8*)(arow + ks * 32);
                acc0 = __builtin_amdgcn_mfma_f32_16x16x32_f16(bfr[0][ks], a, acc0, 0, 0, 0);
                acc1 = __builtin_amdgcn_mfma_f32_16x16x32_f16(bfr[1][ks], a, acc1, 0, 0, 0);
                acc2 = __builtin_amdgcn_mfma_f32_16x16x32_f16(bfr[2][ks], a, acc2, 0, 0, 0);
                acc3 = __builtin_amdgcn_mfma_f32_16x16x32_f16(bfr[3][ks], a, acc3, 0, 0, 0);
            }
            #pragma unroll
            for (int ks = 0; ks < KSLDS; ++ks) {
                f16x8 a  = *(const f16x8*)(arow + (KSREG + ks) * 32);
                f16x8 b0 = *(const f16x8*)(wlds + ((((wave * 4 + 0) * KSLDS + ks) * 64 + lane) << 3));
                f16x8 b1 = *(const f16x8*)(wlds + ((((wave * 4 + 1) * KSLDS + ks) * 64 + lane) << 3));
                f16x8 b2 = *(const f16x8*)(wlds + ((((wave * 4 + 2) * KSLDS + ks) * 64 + lane) << 3));
                f16x8 b3 = *(const f16x8*)(wlds + ((((wave * 4 + 3) * KSLDS + ks) * 64 + lane) << 3));
                acc0 = __builtin_amdgcn_mfma_f32_16x16x32_f16(b0, a, acc0, 0, 0, 0);
                acc1 = __builtin_amdgcn_mfma_f32_16x16x32_f16(b1, a, acc1, 0, 0, 0);
                acc2 = __builtin_amdgcn_mfma_f32_16x16x32_f16(b2, a, acc2, 0, 0, 0);
                acc3 = __builtin_amdgcn_mfma_f32_16x16x32_f16(b3, a, acc3, 0, 0, 0);
            }
        }

        // P addend for THIS step: issued post-MFMA, consumed right after the
        // barrier -> latency hides under barrier convergence; short live range.
        const int  tok = xin[lrow * SS + st];
        const f16* pb  = pbase + (size_t)tok * HH;
        f16x4 pv0 = *(const f16x4*)(pb);
        f16x4 pv1 = *(const f16x4*)(pb + 16);
        f16x4 pv2 = *(const f16x4*)(pb + 32);
        f16x4 pv3 = *(const f16x4*)(pb + 48);

        __syncthreads();  // all waves done reading hbuf for this step

        // ---- epilogue: h_{st+1}[lrow][n0w+16t+4q+r] = tanh(acc{t}[r] + P)
        const int tp1 = st + 1;
        const bool wr_last = (mylen == tp1);
        #pragma unroll
        for (int t = 0; t < 4; ++t) {
            const f32x4 acc = (t == 0) ? acc0 : (t == 1) ? acc1 : (t == 2) ? acc2 : acc3;
            const f16x4 pv  = (t == 0) ? pv0  : (t == 1) ? pv1  : (t == 2) ? pv2  : pv3;
            f16x4 hv;
            #pragma unroll
            for (int r = 0; r < 4; ++r) {
                float z = acc[r] + (float)pv[r];
                // tanh(z) = 1 - 2/(e^{2z}+1); exp over/underflow saturate correctly
                float e = __expf(2.f * z);
                hv[r] = (f16)(1.f - 2.f / (e + 1.f));
            }
            *(f16x4*)(hwr + 16 * t) = hv;
            if (wr_last) *(f16x4*)(lwr + 16 * t) = hv;
        }

        __syncthreads();  // epilogue done: next step may read new hbuf
    }
}

// ---------------------------------------------------------------------------
// MLP layer 1 via MFMA: hidden = relu(last @ W1^T + b1). 512 blocks,
// block = (group g of 16 rows) x (slice of 64 cols); wave owns ONE 16-col
// tile -> bfr[16] = 64 VGPR, fits the 128-reg default budget.
// ---------------------------------------------------------------------------
__global__ __launch_bounds__(256, 1)
void mlp1_kernel(
    const f16* __restrict__ last, const float* __restrict__ W1,
    const float* __restrict__ b1, f16* __restrict__ hidden)
{
    __shared__ __align__(16) f16 hb[16 * HSTR];
    const int tid   = threadIdx.x;
    const int g     = blockIdx.x & 63;
    const int slice = blockIdx.x >> 6;       // 0..7
    const int r0    = g * 16;
    const int n0    = slice * 64;
    const int wave  = tid >> 6;              // 0..3
    const int lane  = tid & 63;
    const int lrow  = lane & 15;
    const int quad  = lane >> 4;

    f16x8 bfr[16];
    {
        const float* wr = W1 + (size_t)(n0 + wave * 16 + lrow) * HH + quad * 8;
        #pragma unroll
        for (int K0 = 0; K0 < 16; ++K0) {
            float4 x0 = *(const float4*)(wr + K0 * 32);
            float4 x1 = *(const float4*)(wr + K0 * 32 + 4);
            f16x8 b;
            b[0] = (f16)x0.x; b[1] = (f16)x0.y; b[2] = (f16)x0.z; b[3] = (f16)x0.w;
            b[4] = (f16)x1.x; b[5] = (f16)x1.y; b[6] = (f16)x1.z; b[7] = (f16)x1.w;
            bfr[K0] = b;
        }
    }

    for (int i = tid; i < 16 * (HH / 8); i += 256) {
        const int row = i >> 6;
        const int c8  = (i & 63) * 8;
        *(float4*)(hb + row * HSTR + c8) =
            *(const float4*)(last + (size_t)(r0 + row) * HH + c8);
    }
    __syncthreads();

    f32x4 acc = {0,0,0,0};
    const f16* arow = hb + lrow * HSTR + quad * 8;
    #pragma unroll
    for (int K0 = 0; K0 < 16; ++K0) {
        f16x8 a = *(const f16x8*)(arow + K0 * 32);
        acc = __builtin_amdgcn_mfma_f32_16x16x32_f16(a, bfr[K0], acc, 0, 0, 0);
    }
    {
        const int cloc = wave * 16 + lrow;
        const float bb = b1[n0 + cloc];
        #pragma unroll
        for (int r = 0; r < 4; ++r) {
            const int row = quad * 4 + r;
            hidden[(size_t)(r0 + row) * HH + n0 + cloc] =
                (f16)fmaxf(acc[r] + bb, 0.f);
        }
    }
}

// ---------------------------------------------------------------------------
// logits = hidden @ W2^T + b2  (1024x32, K=512) — small, fp32 VALU
// ---------------------------------------------------------------------------
__global__ __launch_bounds__(256) void mlp2_kernel(
    const f16* __restrict__ hidden, const float* __restrict__ W2,
    const float* __restrict__ b2, float* __restrict__ out)
{
    __shared__ float hs[8][512];
    const int b0 = blockIdx.x * 8;
    for (int i = threadIdx.x; i < 8 * 512; i += 256)
        hs[i >> 9][i & 511] = (float)hidden[(size_t)(b0 + (i >> 9)) * HH + (i & 511)];
    __syncthreads();
    const int r = threadIdx.x >> 5, c = threadIdx.x & 31;
    const float4* w = (const float4*)(W2 + (size_t)c * HH);
    float acc = 0.f;
    #pragma unroll 4
    for (int k4 = 0; k4 < 128; ++k4) {
        float4 wv = w[k4];
        float4 hv = *(const float4*)(&hs[r][k4 * 4]);
        acc += wv.x * hv.x + wv.y * hv.y + wv.z * hv.z + wv.w * hv.w;
    }
    out[(size_t)(b0 + r) * CC + c] = acc + b2[c];
}

// ---------------------------------------------------------------------------
extern "C" void kernel_launch(void* const* d_in, const int* in_sizes, int n_in,
                              void* d_out, int out_size, void* d_ws, size_t ws_size,
                              hipStream_t stream)
{
    const int*   x_in   = (const int*)d_in[0];
    const int*   x_lens = (const int*)d_in[1];
    const float* emb    = (const float*)d_in[2];
    const float* W_ih   = (const float*)d_in[3];
    const float* b_ih   = (const float*)d_in[4];
    const float* W_hh   = (const float*)d_in[5];
    const float* b_hh   = (const float*)d_in[6];
    const float* W1     = (const float*)d_in[7];
    const float* b1     = (const float*)d_in[8];
    const float* W2     = (const float*)d_in[9];
    const float* b2     = (const float*)d_in[10];
    float* out = (float*)d_out;

    // workspace carve (re-poisoned every launch; everything rewritten below).
    // Wf overlaps the `hidden` slot: Wf is consumed only by rnn_kernel, and
    // hidden is written only afterwards by mlp1 (same-stream ordering).
    char* ws = (char*)d_ws;
    f16* P      = (f16*)ws;                             // 128 KiB (slot 256 KiB)
    f16* last   = (f16*)(ws + (256 << 10));             // 1 MiB
    f16* hidden = (f16*)(ws + (256 << 10) + (1 << 20)); // 1 MiB
    f16* Wf     = hidden;                               // 512 KiB, rnn-init only

    hipLaunchKernelGGL(prep_P, dim3(VV), dim3(256), 0, stream,
                       emb, W_ih, b_ih, b_hh, P);
    hipLaunchKernelGGL(prep_W, dim3(256), dim3(256), 0, stream,
                       W_hh, Wf);
    hipLaunchKernelGGL(rnn_kernel, dim3(BB / 16), dim3(512), 0, stream,
                       x_in, x_lens, Wf, P, last);
    hipLaunchKernelGGL(mlp1_kernel, dim3(512), dim3(256), 0, stream,
                       last, W1, b1, hidden);
    hipLaunchKernelGGL(mlp2_kernel, dim3(BB / 8), dim3(256), 0, stream,
                       hidden, W2, b2, out);
}

// Round 8
// 278.005 us; speedup vs baseline: 1.1789x; 1.0772x over previous
//
#include <hip/hip_runtime.h>
#include <hip/hip_bf16.h>

// Problem: B=1024, S=64, E=256, H=512, V=128, C=32
#define BB 1024
#define SS 64
#define EE 256
#define HH 512
#define VV 128
#define CC 32

typedef _Float16 f16;
typedef _Float16 f16x4 __attribute__((ext_vector_type(4)));
typedef _Float16 f16x8 __attribute__((ext_vector_type(8)));
typedef float    f32x4 __attribute__((ext_vector_type(4)));

// ---------------------------------------------------------------------------
// ONE prep launch:
//   blocks 0..127   : P[v][h] = emb[v,:] . W_ih[h,:] + b_ih[h] + b_hh[h]
//   blocks 128..223 : f32->f16 tables  Whf = W_hh, W1f = W1, W2f = W2
// (merging removes 1 launch + gap; tables make all weight streams clean
//  b128 f16 loads in the fused kernel)
// ---------------------------------------------------------------------------
#define CVT_TOT4   (65536 + 65536 + 4096)   // float4 units: W_hh, W1, W2
#define CVT_STRIDE (96 * 256)

__global__ __launch_bounds__(256) void prep_kernel(
    const float* __restrict__ emb, const float* __restrict__ W_ih,
    const float* __restrict__ b_ih, const float* __restrict__ b_hh,
    const float* __restrict__ W_hh, const float* __restrict__ W1,
    const float* __restrict__ W2,
    f16* __restrict__ P, f16* __restrict__ Whf,
    f16* __restrict__ W1f, f16* __restrict__ W2f)
{
    if (blockIdx.x < VV) {
        __shared__ float er[EE];
        const int v = blockIdx.x;
        for (int i = threadIdx.x; i < EE; i += 256) er[i] = emb[(size_t)v * EE + i];
        __syncthreads();
        for (int h = threadIdx.x; h < HH; h += 256) {
            const float4* wr = (const float4*)(W_ih + (size_t)h * EE);
            float s = 0.f;
            #pragma unroll 4
            for (int e4 = 0; e4 < EE / 4; ++e4) {
                float4 w = wr[e4];
                const float* e = er + e4 * 4;
                s += w.x * e[0] + w.y * e[1] + w.z * e[2] + w.w * e[3];
            }
            P[(size_t)v * HH + h] = (f16)(s + b_ih[h] + b_hh[h]);
        }
    } else {
        for (int i = (blockIdx.x - VV) * 256 + threadIdx.x; i < CVT_TOT4;
             i += CVT_STRIDE) {
            const float* src; f16* dst; int j;
            if (i < 65536)       { src = W_hh; dst = Whf; j = i; }
            else if (i < 131072) { src = W1;   dst = W1f; j = i - 65536; }
            else                 { src = W2;   dst = W2f; j = i - 131072; }
            float4 x = ((const float4*)src)[j];
            f16x4 y;
            y[0] = (f16)x.x; y[1] = (f16)x.y; y[2] = (f16)x.z; y[3] = (f16)x.w;
            *(f16x4*)(dst + (size_t)j * 4) = y;
        }
    }
}

// ---------------------------------------------------------------------------
// RNN + fused MLP head. 64 blocks x 512 threads (8 waves). Block owns 16
// batch rows, computes ALL 512 h-cols. W_hh: k 0..383 in regs (bfr[4][12] =
// 192 VGPR-equivalents), k 384..511 in LDS (128 KB).
//
// REGISTER STRATEGY (proven round 7): attributes cannot move the allocator
// off its 128-VGPR target; the ONE inline-asm per iteration with all 48
// fragments as "v" inputs forces 192 regs simultaneously live -> the
// 128-reg plan is infeasible -> overflow goes to AGPRs (unified file,
// reg-to-reg moves, no scratch). Verified: WRITE_SIZE 24.7 MB -> 1.0 MB.
//
// FUSION (this round): `last` is kept in 8 regs/lane (each lane owns its
// own (row,col) slots). After the loop: lastreg -> hbuf redistribute ->
// mlp1 (A from hbuf, B = W1f streamed from L2, MFMA, relu) -> hidden into
// the dead wlds region -> mlp2 on waves 0..1 -> out. Removes 2 kernel
// launches, mlp1's 64 MB of redundant W1 traffic, last/hidden round-trips.
//
// MFMA operands SWAPPED: D = W_tile * h^T.
//   lane(lrow,quad), reg r -> h_next[batch=lrow][col = n0w + 16t + 4*quad + r]
// ---------------------------------------------------------------------------
#define KSREG 12           // k-steps (of 32) held in registers
#define KSLDS 4            // k-steps held in LDS
#define HSTR  520          // hbuf stride in f16 (1040 B: 8B-aligned, +4-bank skew)

// the 48-operand residency-forcing asm (see comment above)
#define KB(t,k) "v"(bfr[t][k])
#define KBT(t)  KB(t,0), KB(t,1), KB(t,2), KB(t,3), KB(t,4), KB(t,5), \
                KB(t,6), KB(t,7), KB(t,8), KB(t,9), KB(t,10), KB(t,11)

__global__
__attribute__((amdgpu_flat_work_group_size(512, 512)))
__attribute__((amdgpu_waves_per_eu(2, 2)))
void rnn_fused(
    const int* __restrict__ x_in, const int* __restrict__ x_lens,
    const f16* __restrict__ Whf, const f16* __restrict__ P,
    const f16* __restrict__ W1f, const float* __restrict__ b1,
    const f16* __restrict__ W2f, const float* __restrict__ b2,
    float* __restrict__ out)
{
    __shared__ __align__(16) f16 hbuf[16 * HSTR];                // 16.3 KB
    __shared__ __align__(16) f16 wlds[8 * 4 * KSLDS * 64 * 8];   // 128 KB
    __shared__ int xin[16 * SS];                                 // 4 KB
    __shared__ int lens[16];

    const int tid  = threadIdx.x;
    const int r0   = blockIdx.x * 16;
    const int wave = tid >> 6;       // 0..7 -> cols [64w, 64w+64)
    const int lane = tid & 63;
    const int lrow = lane & 15;      // batch row (as B-operand n / C col)
    const int quad = lane >> 4;
    const int n0w  = wave * 64;

    // ---- one-time: Whf -> register fragments + LDS fragments ----
    // frag[k][n] = W_hh[n][k]; lane holds n = lrow (+16t+64w), k = 32ks+8quad+j
    f16x8 bfr[4][KSREG];
    #pragma unroll
    for (int t = 0; t < 4; ++t) {
        const f16* wr = Whf + (size_t)(n0w + 16 * t + lrow) * HH + quad * 8;
        #pragma unroll
        for (int ks = 0; ks < KSREG; ++ks)
            bfr[t][ks] = *(const f16x8*)(wr + ks * 32);
        #pragma unroll
        for (int ks = 0; ks < KSLDS; ++ks)
            // swizzled: lane-consecutive 16B chunks, conflict-free b128 reads
            *(f16x8*)(wlds + ((((wave * 4 + t) * KSLDS + ks) * 64 + lane) << 3)) =
                *(const f16x8*)(wr + (KSREG + ks) * 32);
    }

    // ---- LDS init: token tile, lengths (hbuf needs no init: st=0 writes all)
    for (int i = tid; i < 16 * (SS / 4); i += 512)
        ((int4*)xin)[i] = ((const int4*)(x_in + (size_t)r0 * SS))[i];
    if (tid < 16) lens[tid] = x_lens[r0 + tid];
    __syncthreads();

    const int   mylen = lens[lrow];
    const f16*  arow  = hbuf + lrow * HSTR + quad * 8;           // B-operand reads
    f16*        hwr   = hbuf + lrow * HSTR + n0w + quad * 4;     // epilogue writes
    const f16*  pbase = P + n0w + quad * 4;

    f16x4 lastreg[4];    // this lane's slots of last = h_{len-1}

    for (int st = 0; st < SS; ++st) {
        // Force all 48 W fragments simultaneously resident at ONE instruction
        // each iteration: defeats the allocator's spill-to-128 plan (see top).
        asm volatile("" :: KBT(0), KBT(1), KBT(2), KBT(3));

        // ---- MFMA: D = W_tile * h^T, 64 cols/wave x 16 rows, K = 512 ----
        f32x4 acc0 = {0,0,0,0}, acc1 = {0,0,0,0}, acc2 = {0,0,0,0}, acc3 = {0,0,0,0};
        if (st) {   // h_0 = 0 -> skip the whole matmul at step 0
            #pragma unroll
            for (int ks = 0; ks < KSREG; ++ks) {
                f16x8 a = *(const f16x8*)(arow + ks * 32);
                acc0 = __builtin_amdgcn_mfma_f32_16x16x32_f16(bfr[0][ks], a, acc0, 0, 0, 0);
                acc1 = __builtin_amdgcn_mfma_f32_16x16x32_f16(bfr[1][ks], a, acc1, 0, 0, 0);
                acc2 = __builtin_amdgcn_mfma_f32_16x16x32_f16(bfr[2][ks], a, acc2, 0, 0, 0);
                acc3 = __builtin_amdgcn_mfma_f32_16x16x32_f16(bfr[3][ks], a, acc3, 0, 0, 0);
            }
            #pragma unroll
            for (int ks = 0; ks < KSLDS; ++ks) {
                f16x8 a  = *(const f16x8*)(arow + (KSREG + ks) * 32);
                f16x8 b0 = *(const f16x8*)(wlds + ((((wave * 4 + 0) * KSLDS + ks) * 64 + lane) << 3));
                f16x8 b1 = *(const f16x8*)(wlds + ((((wave * 4 + 1) * KSLDS + ks) * 64 + lane) << 3));
                f16x8 b2 = *(const f16x8*)(wlds + ((((wave * 4 + 2) * KSLDS + ks) * 64 + lane) << 3));
                f16x8 b3 = *(const f16x8*)(wlds + ((((wave * 4 + 3) * KSLDS + ks) * 64 + lane) << 3));
                acc0 = __builtin_amdgcn_mfma_f32_16x16x32_f16(b0, a, acc0, 0, 0, 0);
                acc1 = __builtin_amdgcn_mfma_f32_16x16x32_f16(b1, a, acc1, 0, 0, 0);
                acc2 = __builtin_amdgcn_mfma_f32_16x16x32_f16(b2, a, acc2, 0, 0, 0);
                acc3 = __builtin_amdgcn_mfma_f32_16x16x32_f16(b3, a, acc3, 0, 0, 0);
            }
        }

        // P addend for THIS step: issued post-MFMA, consumed right after the
        // barrier -> latency hides under barrier convergence; short live range.
        const int  tok = xin[lrow * SS + st];
        const f16* pb  = pbase + (size_t)tok * HH;
        f16x4 pv0 = *(const f16x4*)(pb);
        f16x4 pv1 = *(const f16x4*)(pb + 16);
        f16x4 pv2 = *(const f16x4*)(pb + 32);
        f16x4 pv3 = *(const f16x4*)(pb + 48);

        __syncthreads();  // all waves done reading hbuf for this step

        // ---- epilogue: h_{st+1}[lrow][n0w+16t+4q+r] = tanh(acc{t}[r] + P)
        const int tp1 = st + 1;
        const bool wr_last = (mylen == tp1);
        #pragma unroll
        for (int t = 0; t < 4; ++t) {
            const f32x4 acc = (t == 0) ? acc0 : (t == 1) ? acc1 : (t == 2) ? acc2 : acc3;
            const f16x4 pv  = (t == 0) ? pv0  : (t == 1) ? pv1  : (t == 2) ? pv2  : pv3;
            f16x4 hv;
            #pragma unroll
            for (int r = 0; r < 4; ++r) {
                float z = acc[r] + (float)pv[r];
                // tanh(z) = 1 - 2/(e^{2z}+1); exp over/underflow saturate correctly
                float e = __expf(2.f * z);
                hv[r] = (f16)(1.f - 2.f / (e + 1.f));
            }
            *(f16x4*)(hwr + 16 * t) = hv;
            if (wr_last) lastreg[t] = hv;
        }

        __syncthreads();  // epilogue done: next step may read new hbuf
    }

    // ======================= fused MLP head =======================
    // 1) redistribute last (in regs) into hbuf (h_64 no longer needed)
    #pragma unroll
    for (int t = 0; t < 4; ++t)
        *(f16x4*)(hwr + 16 * t) = lastreg[t];
    __syncthreads();

    // 2) mlp1: hidden = relu(last @ W1^T + b1); A from hbuf, B = W1f (L2)
    //    same wave->col mapping as the rnn step; hidden -> dead wlds region
    f16* hid = wlds;                       // 16 x HSTR f16, reuse
    {
        f32x4 acc0 = {0,0,0,0}, acc1 = {0,0,0,0}, acc2 = {0,0,0,0}, acc3 = {0,0,0,0};
        #pragma unroll 4
        for (int ks = 0; ks < 16; ++ks) {
            f16x8 a  = *(const f16x8*)(arow + ks * 32);
            const f16* w1r = W1f + (size_t)(n0w + lrow) * HH + ks * 32 + quad * 8;
            f16x8 b0 = *(const f16x8*)(w1r);
            f16x8 b1 = *(const f16x8*)(w1r + 16 * HH);
            f16x8 b2 = *(const f16x8*)(w1r + 32 * HH);
            f16x8 b3 = *(const f16x8*)(w1r + 48 * HH);
            acc0 = __builtin_amdgcn_mfma_f32_16x16x32_f16(b0, a, acc0, 0, 0, 0);
            acc1 = __builtin_amdgcn_mfma_f32_16x16x32_f16(b1, a, acc1, 0, 0, 0);
            acc2 = __builtin_amdgcn_mfma_f32_16x16x32_f16(b2, a, acc2, 0, 0, 0);
            acc3 = __builtin_amdgcn_mfma_f32_16x16x32_f16(b3, a, acc3, 0, 0, 0);
        }
        __syncthreads();   // all waves done reading hbuf(last) AND rnn wlds
        f16* hwr2 = hid + lrow * HSTR + n0w + quad * 4;
        #pragma unroll
        for (int t = 0; t < 4; ++t) {
            const f32x4 acc = (t == 0) ? acc0 : (t == 1) ? acc1 : (t == 2) ? acc2 : acc3;
            const float4 bv = *(const float4*)(b1 + n0w + 16 * t + quad * 4);
            const float  bb[4] = {bv.x, bv.y, bv.z, bv.w};
            f16x4 hv;
            #pragma unroll
            for (int r = 0; r < 4; ++r)
                hv[r] = (f16)fmaxf(acc[r] + bb[r], 0.f);
            *(f16x4*)(hwr2 + 16 * t) = hv;
        }
    }
    __syncthreads();

    // 3) mlp2: logits = hidden @ W2^T + b2  (16 rows x 32 cols, K=512)
    //    waves 0..1 each own a 16-col tile; others done.
    if (wave < 2) {
        const f16* harow = hid + lrow * HSTR + quad * 8;
        f32x4 acc = {0,0,0,0};
        #pragma unroll 4
        for (int ks = 0; ks < 16; ++ks) {
            f16x8 a = *(const f16x8*)(harow + ks * 32);
            f16x8 b = *(const f16x8*)(W2f + (size_t)(wave * 16 + lrow) * HH
                                      + ks * 32 + quad * 8);
            acc = __builtin_amdgcn_mfma_f32_16x16x32_f16(b, a, acc, 0, 0, 0);
        }
        const float4 bv = *(const float4*)(b2 + wave * 16 + quad * 4);
        float4 o;
        o.x = acc[0] + bv.x; o.y = acc[1] + bv.y;
        o.z = acc[2] + bv.z; o.w = acc[3] + bv.w;
        *(float4*)(out + (size_t)(r0 + lrow) * CC + wave * 16 + quad * 4) = o;
    }
}

// ---------------------------------------------------------------------------
extern "C" void kernel_launch(void* const* d_in, const int* in_sizes, int n_in,
                              void* d_out, int out_size, void* d_ws, size_t ws_size,
                              hipStream_t stream)
{
    const int*   x_in   = (const int*)d_in[0];
    const int*   x_lens = (const int*)d_in[1];
    const float* emb    = (const float*)d_in[2];
    const float* W_ih   = (const float*)d_in[3];
    const float* b_ih   = (const float*)d_in[4];
    const float* W_hh   = (const float*)d_in[5];
    const float* b_hh   = (const float*)d_in[6];
    const float* W1     = (const float*)d_in[7];
    const float* b1     = (const float*)d_in[8];
    const float* W2     = (const float*)d_in[9];
    const float* b2     = (const float*)d_in[10];
    float* out = (float*)d_out;

    // workspace carve (re-poisoned every launch; all tables rebuilt by prep)
    char* ws = (char*)d_ws;
    f16* P   = (f16*)ws;                              // 128 KiB (slot 256 KiB)
    f16* Whf = (f16*)(ws + (256 << 10));              // 512 KiB
    f16* W1f = (f16*)(ws + (256 << 10) + (512 << 10));// 512 KiB
    f16* W2f = (f16*)(ws + (256 << 10) + (1 << 20));  // 32 KiB

    hipLaunchKernelGGL(prep_kernel, dim3(VV + 96), dim3(256), 0, stream,
                       emb, W_ih, b_ih, b_hh, W_hh, W1, W2, P, Whf, W1f, W2f);
    hipLaunchKernelGGL(rnn_fused, dim3(BB / 16), dim3(512), 0, stream,
                       x_in, x_lens, Whf, P, W1f, b1, W2f, b2, out);
}